// Round 11
// baseline (150.645 us; speedup 1.0000x reference)
//
#include <hip/hip_runtime.h>

typedef _Float16 half8 __attribute__((ext_vector_type(8)));
typedef float f32x4 __attribute__((ext_vector_type(4)));

#define NN 4096
#define NE 512
#define HD 64
#define WSCALE (1.0f / 256.0f)

// --- f16 helpers: RN hi + RN residual lo ---
__device__ __forceinline__ void f16_split(float f, _Float16& hi, _Float16& lo) {
    hi = (_Float16)f;                    // v_cvt_f16_f32 (RN)
    lo = (_Float16)(f - (float)hi);
}

#define MFMA16(a, b, c) __builtin_amdgcn_mfma_f32_16x16x32_f16((a), (b), (c), 0, 0, 0)

// ---------------------------------------------------------------------------
// prepA: blocks 0..47    : W=[Wq|Wk|Wv] -> B-frag f16 (ntiles 0-3 Wq, 4-7 Wk,
//                          8-11 Wv).  [kt(16)][nt(12)][lane(64)][j(8)]
//        blocks 48..559  : x -> A-frag f16 hi/lo. [rt(512)][kt(16)][L(64)][j(8)]
//        blocks 560..623 : xsum partials: xpart[i][k] = sum of 128 x rows.
// ---------------------------------------------------------------------------
__global__ __launch_bounds__(256) void prepA_kernel(
    const float* __restrict__ x,
    const float* __restrict__ Wq, const float* __restrict__ Wk,
    const float* __restrict__ Wv,
    _Float16* __restrict__ Wf,
    _Float16* __restrict__ Xfhi, _Float16* __restrict__ Xflo,
    float* __restrict__ xpart)
{
    const int blk = blockIdx.x;
    if (blk < 48) {
        const int gtid = blk * 256 + threadIdx.x;   // [0, 12288)
        const int L = gtid & 63;
        const int nt = (gtid >> 6) % 12;
        const int kt = gtid / 768;
        const int n = nt * 16 + (L & 15);
        const int kbase = kt * 32 + (L >> 4) * 8;
        const float* src; int col;
        if (n < 64)       { src = Wq; col = n; }
        else if (n < 128) { src = Wk; col = n - 64; }
        else              { src = Wv; col = n - 128; }
        half8 sh;
#pragma unroll
        for (int j = 0; j < 8; ++j)
            sh[j] = (_Float16)src[(size_t)(kbase + j) * HD + col];
        *(half8*)(Wf + (size_t)gtid * 8) = sh;
    } else if (blk < 560) {
        const int gt = (blk - 48) * 256 + threadIdx.x;   // [0, 131072)
#pragma unroll
        for (int i = 0; i < 4; ++i) {
            const int s = gt + i * 131072;               // slot [0, 524288)
            const int rt = s >> 10;
            const int kt = (s >> 6) & 15;
            const int L = s & 63;
            const int row = rt * 16 + (L & 15);
            const int k = kt * 32 + (L >> 4) * 8;
            const float4 x0 = *(const float4*)(x + (size_t)row * NE + k);
            const float4 x1 = *(const float4*)(x + (size_t)row * NE + k + 4);
            const float xv[8] = {x0.x, x0.y, x0.z, x0.w,
                                 x1.x, x1.y, x1.z, x1.w};
            half8 hh, ll;
#pragma unroll
            for (int j = 0; j < 8; ++j) {
                _Float16 h, l; f16_split(xv[j], h, l);
                hh[j] = h; ll[j] = l;
            }
            *(half8*)(Xfhi + (size_t)s * 8) = hh;
            *(half8*)(Xflo + (size_t)s * 8) = ll;
        }
    } else {
        const int i = blk - 560;         // 0..63 = b*32 + seg
        const int b = i >> 5, seg = i & 31;
        const int t = threadIdx.x;       // cols 2t, 2t+1
        const float* xb = x + ((size_t)b * NN + seg * 128) * NE + 2 * t;
        float s0 = 0.f, s1 = 0.f;
#pragma unroll 8
        for (int r = 0; r < 128; ++r) {
            const float2 v = *(const float2*)(xb + (size_t)r * NE);
            s0 += v.x; s1 += v.y;
        }
        xpart[(size_t)i * 512 + 2 * t]     = s0;
        xpart[(size_t)i * 512 + 2 * t + 1] = s1;
    }
}

// ---------------------------------------------------------------------------
// prepB: blocks 0..17  : V129 = x[0:144]@Wv + bv via MFMA (Xf + Wf ntiles
//                        8..11), C-frags -> LDS -> Vf B-frag emission.
//        blocks 18..19 : Vf ones plane (nt=4).
//        block  20     : xsum[b][k] = sum of 32 xpart segments.
// Vf layout: [b(2)][jt(5)][nt(5)][lane(64)][jj(8)]
// ---------------------------------------------------------------------------
__global__ __launch_bounds__(256) void prepB_kernel(
    const _Float16* __restrict__ Xfhi, const _Float16* __restrict__ Xflo,
    const _Float16* __restrict__ Wf, const float* __restrict__ bv,
    const float* __restrict__ xpart,
    _Float16* __restrict__ Vf, float* __restrict__ xsum)
{
    const int blk = blockIdx.x;
    const int tid = threadIdx.x;
    if (blk < 18) {
        __shared__ float V_lds[16][68];
        const int b = blk / 9, rt = blk % 9;
        const int L = tid & 63, w = tid >> 6;
        const int m = L & 15, kg = L >> 4;
        const int rtg = b * 256 + rt;
        f32x4 acc = (f32x4){0.f, 0.f, 0.f, 0.f};
#pragma unroll
        for (int kt = 0; kt < 16; ++kt) {
            const size_t ao = (((size_t)rtg * 16 + kt) * 64 + L) * 8;
            const half8 ahi = *(const half8*)(Xfhi + ao);
            const half8 alo = *(const half8*)(Xflo + ao);
            const half8 wv = *(const half8*)(Wf + (((size_t)kt * 12 + 8 + w) * 64 + L) * 8);
            acc = MFMA16(ahi, wv, acc);
            acc = MFMA16(alo, wv, acc);
        }
        const float bvd = bv[w * 16 + m];
#pragma unroll
        for (int r = 0; r < 4; ++r)
            V_lds[kg * 4 + r][w * 16 + m] = acc[r] + bvd;
        __syncthreads();
        if (rt < 8) {
            const int jt = rt >> 1;
            if ((kg >> 1) == (rt & 1)) {
                const int nt = w;
                half8 sh;
#pragma unroll
                for (int jj = 0; jj < 8; ++jj)
                    sh[jj] = (_Float16)V_lds[(kg - (rt & 1) * 2) * 8 + jj][nt * 16 + m];
                *(half8*)(Vf + ((size_t)((b * 25 + jt * 5 + nt) * 64 + L)) * 8) = sh;
            }
        } else {   // rt == 8: jt=4 plane, only j==128 real; rest zero
            const int nt = w;
            half8 sh = {0, 0, 0, 0, 0, 0, 0, 0};
            if (kg == 0) sh[0] = (_Float16)V_lds[0][nt * 16 + m];
            *(half8*)(Vf + ((size_t)((b * 25 + 4 * 5 + nt) * 64 + L)) * 8) = sh;
        }
    } else if (blk < 20) {
        const int b = blk - 18;
        const int L = tid & 63;
        for (int jt = tid >> 6; jt < 5; jt += 4) {
            half8 sh = {0, 0, 0, 0, 0, 0, 0, 0};
            if ((L & 15) == 0) {
#pragma unroll
                for (int jj = 0; jj < 8; ++jj) {
                    const int j = jt * 32 + (L >> 4) * 8 + jj;
                    if (j < 129) sh[jj] = (_Float16)1.0f;
                }
            }
            *(half8*)(Vf + ((size_t)((b * 25 + jt * 5 + 4) * 64 + L)) * 8) = sh;
        }
    } else {
        for (int o = tid; o < 1024; o += 256) {
            const int b = o >> 9, k = o & 511;
            float s = 0.f;
#pragma unroll 8
            for (int seg = 0; seg < 32; ++seg)
                s += xpart[(size_t)(b * 32 + seg) * 512 + k];
            xsum[o] = s;
        }
    }
}

// ---------------------------------------------------------------------------
// fused: grid 512 (b = blk>>8, 16 queries/block), block 256 (4 waves).
// Per block: recompute K-slab (160 rows, wave w = d-ntile w) and Q-tile
// locally via MFMA from Xf+Wf (MFMA is at 2% util — free); C-frags ->
// LDS transpose (col=lane&15, row=quad*4+reg, HW-verified mapping) ->
// B/A-frags for QK^T. Vs computed inline from xsum (Wv L1-hot).
// OOB keys: rowtile clamp + mask at exp (w=0), matching reference.
// No Q/K global round-trip, no cross-kernel gap for it.
// ---------------------------------------------------------------------------
__global__ __launch_bounds__(256) void fused_kernel(
    const _Float16* __restrict__ Xfhi, const _Float16* __restrict__ Xflo,
    const _Float16* __restrict__ Wf,
    const float* __restrict__ bq, const float* __restrict__ bk,
    const float* __restrict__ Wv, const float* __restrict__ bv,
    const float* __restrict__ xsum, const _Float16* __restrict__ Vf,
    float* __restrict__ out)
{
    __shared__ __align__(16) _Float16 K_lds[160][72];
    __shared__ float Q_lds[16][68];
    __shared__ __align__(16) _Float16 wt_hi[16 * 168];
    __shared__ __align__(16) _Float16 wt_lo[16 * 168];
    __shared__ float den_lds[16];
    __shared__ float vs_lds[4][64];

    const int tid = threadIdx.x;
    const int L = tid & 63;
    const int w = tid >> 6;
    const int m = L & 15, kg = L >> 4;
    const int b = blockIdx.x >> 8;
    const int n0 = (blockIdx.x & 255) * 16;
    const int rt0 = n0 >> 4;

    // V-frag loads upfront (independent of everything below)
    half8 vhi[5], vh4[5];
#pragma unroll
    for (int jt = 0; jt < 5; ++jt) {
        const size_t fo = ((size_t)((b * 25 + jt * 5 + w) * 64 + L)) * 8;
        vhi[jt] = *(const half8*)(Vf + fo);
    }
    if (w == 0) {
#pragma unroll
        for (int jt = 0; jt < 5; ++jt) {
            const size_t fo4 = ((size_t)((b * 25 + jt * 5 + 4) * 64 + L)) * 8;
            vh4[jt] = *(const half8*)(Vf + fo4);
        }
    }

    // zero the (q,j) weight buffer (j in [129,168) must read as 0)
    for (int i = tid; i < (16 * 168) / 2; i += 256) {
        ((int*)wt_hi)[i] = 0;
        ((int*)wt_lo)[i] = 0;
    }

    // ---- K-slab GEMM: wave w owns K d-ntile w, 10 rowtiles ----
    {
        const float bkd = bk[w * 16 + m];
        for (int rt = 0; rt < 10; ++rt) {
            int lrt = rt0 - 4 + rt;
            lrt = (lrt < 0) ? 0 : (lrt > 255 ? 255 : lrt);   // masked at exp
            const int rtg = b * 256 + lrt;
            f32x4 acc = (f32x4){0.f, 0.f, 0.f, 0.f};
#pragma unroll
            for (int kt = 0; kt < 16; ++kt) {
                const size_t ao = (((size_t)rtg * 16 + kt) * 64 + L) * 8;
                const half8 ahi = *(const half8*)(Xfhi + ao);
                const half8 alo = *(const half8*)(Xflo + ao);
                const half8 wv = *(const half8*)(Wf + (((size_t)kt * 12 + 4 + w) * 64 + L) * 8);
                acc = MFMA16(ahi, wv, acc);
                acc = MFMA16(alo, wv, acc);
            }
#pragma unroll
            for (int r = 0; r < 4; ++r)
                K_lds[rt * 16 + kg * 4 + r][w * 16 + m] = (_Float16)(acc[r] + bkd);
        }
    }
    // ---- Q-tile GEMM: wave w owns Q d-ntile w ----
    {
        const int rtg = b * 256 + rt0;
        f32x4 acc = (f32x4){0.f, 0.f, 0.f, 0.f};
#pragma unroll
        for (int kt = 0; kt < 16; ++kt) {
            const size_t ao = (((size_t)rtg * 16 + kt) * 64 + L) * 8;
            const half8 ahi = *(const half8*)(Xfhi + ao);
            const half8 alo = *(const half8*)(Xflo + ao);
            const half8 wv = *(const half8*)(Wf + (((size_t)kt * 12 + w) * 64 + L) * 8);
            acc = MFMA16(ahi, wv, acc);
            acc = MFMA16(alo, wv, acc);
        }
        const float bqd = bq[w * 16 + m];
#pragma unroll
        for (int r = 0; r < 4; ++r)
            Q_lds[kg * 4 + r][w * 16 + m] = acc[r] + bqd;
    }
    // ---- Vs partial: wave w covers k in [w*128, (w+1)*128) ----
    {
        float s = (w == 0) ? 4096.0f * bv[L] : 0.0f;
        const float* xs = xsum + b * 512 + w * 128;
#pragma unroll 8
        for (int k = 0; k < 128; ++k)
            s += xs[k] * Wv[(size_t)(w * 128 + k) * HD + L];
        vs_lds[w][L] = s;
    }
    __syncthreads();

    // ---- phase 1: S = Q.K^T from LDS frags ----
    {
        const float4 qa0 = *(const float4*)(&Q_lds[m][kg * 8]);
        const float4 qa1 = *(const float4*)(&Q_lds[m][kg * 8 + 4]);
        const float4 qb0 = *(const float4*)(&Q_lds[m][32 + kg * 8]);
        const float4 qb1 = *(const float4*)(&Q_lds[m][32 + kg * 8 + 4]);
        const float q0v[8] = {qa0.x, qa0.y, qa0.z, qa0.w, qa1.x, qa1.y, qa1.z, qa1.w};
        const float q1v[8] = {qb0.x, qb0.y, qb0.z, qb0.w, qb1.x, qb1.y, qb1.z, qb1.w};
        half8 qhi0, qlo0, qhi1, qlo1;
#pragma unroll
        for (int j = 0; j < 8; ++j) {
            _Float16 h, l;
            f16_split(q0v[j], h, l); qhi0[j] = h; qlo0[j] = l;
            f16_split(q1v[j], h, l); qhi1[j] = h; qlo1[j] = l;
        }

        const int nkt = (w < 2) ? 3 : 2;
        const int kts[3] = {w, w + 4, w + 8};
#pragma unroll
        for (int i = 0; i < 3; ++i) {
            if (i < nkt) {
                const int kt = kts[i];
                const half8 kh0 = *(const half8*)(&K_lds[kt * 16 + m][kg * 8]);
                const half8 kh1 = *(const half8*)(&K_lds[kt * 16 + m][32 + kg * 8]);
                f32x4 acc = (f32x4){0.f, 0.f, 0.f, 0.f};
                acc = MFMA16(qhi0, kh0, acc);
                acc = MFMA16(qhi1, kh1, acc);
                acc = MFMA16(qlo0, kh0, acc);
                acc = MFMA16(qlo1, kh1, acc);
                const int l = kt * 16 + m;
#pragma unroll
                for (int r = 0; r < 4; ++r) {
                    const int q = kg * 4 + r;
                    const int j = l - q;
                    if (j >= 0 && j < 129) {
                        const int key = n0 - 64 + l;
                        float wval = 0.f;
                        if (key >= 0 && key < NN)
                            wval = (__expf(acc[r]) - 1.0f) * WSCALE;
                        _Float16 hh, ll; f16_split(wval, hh, ll);
                        wt_hi[q * 168 + j] = hh;
                        wt_lo[q * 168 + j] = ll;
                    }
                }
            }
        }
    }
    __syncthreads();

    // ---- phase 2: [out|den] = wt(16x160) @ [V|1|0] ----
    f32x4 oacc = (f32x4){0.f, 0.f, 0.f, 0.f};
    f32x4 dacc = (f32x4){0.f, 0.f, 0.f, 0.f};
#pragma unroll
    for (int jt = 0; jt < 5; ++jt) {
        const half8 whi = *(const half8*)(wt_hi + m * 168 + jt * 32 + kg * 8);
        const half8 wlo = *(const half8*)(wt_lo + m * 168 + jt * 32 + kg * 8);
        oacc = MFMA16(whi, vhi[jt], oacc);
        oacc = MFMA16(wlo, vhi[jt], oacc);
        if (w == 0) {
            dacc = MFMA16(whi, vh4[jt], dacc);
            dacc = MFMA16(wlo, vh4[jt], dacc);
        }
    }
    if (w == 0 && m == 0) {
#pragma unroll
        for (int r = 0; r < 4; ++r) den_lds[kg * 4 + r] = dacc[r];
    }
    __syncthreads();

    // ---- epilogue ----
    {
        const int d = w * 16 + m;
        const float vs = vs_lds[0][d] + vs_lds[1][d] + vs_lds[2][d] + vs_lds[3][d];
#pragma unroll
        for (int r = 0; r < 4; ++r) {
            const int q = kg * 4 + r;
            const float val = (vs + 256.0f * oacc[r])
                            / (4096.f + 256.0f * den_lds[q]);
            out[((size_t)(b * NN + n0 + q)) * HD + d] = val;
        }
    }
}

// ---------------------------------------------------------------------------
extern "C" void kernel_launch(void* const* d_in, const int* in_sizes, int n_in,
                              void* d_out, int out_size, void* d_ws, size_t ws_size,
                              hipStream_t stream)
{
    const float* x  = (const float*)d_in[0];
    const float* Wq = (const float*)d_in[1];
    const float* bq = (const float*)d_in[2];
    const float* Wk = (const float*)d_in[3];
    const float* bk = (const float*)d_in[4];
    const float* Wv = (const float*)d_in[5];
    const float* bv = (const float*)d_in[6];
    float* out = (float*)d_out;

    char* ws = (char*)d_ws;
    _Float16* Wf    = (_Float16*)(ws + 0);          //  196608 B
    _Float16* Xfhi  = (_Float16*)(ws + 196608);     // 8388608 B
    _Float16* Xflo  = (_Float16*)(ws + 8585216);    // 8388608 B
    _Float16* Vf    = (_Float16*)(ws + 16973824);   //   51200 B
    float*    xpart = (float*)(ws + 17025024);      //  131072 B
    float*    xsum  = (float*)(ws + 17156096);      //    4096 B

    prepA_kernel<<<624, 256, 0, stream>>>(x, Wq, Wk, Wv, Wf, Xfhi, Xflo, xpart);
    prepB_kernel<<<21, 256, 0, stream>>>(Xfhi, Xflo, Wf, bv, xpart, Vf, xsum);
    fused_kernel<<<512, 256, 0, stream>>>(Xfhi, Xflo, Wf, bq, bk, Wv, bv,
                                          xsum, Vf, out);
}

// Round 14
// 98.336 us; speedup vs baseline: 1.5319x; 1.5319x over previous
//
#include <hip/hip_runtime.h>

typedef _Float16 half8 __attribute__((ext_vector_type(8)));
typedef float f32x4 __attribute__((ext_vector_type(4)));

#define NN 4096
#define NE 512
#define HD 64
#define KROWS 4288   // 64 pad + 4096 + 128 pad (per batch)
#define KOFF  64
#define WSCALE (1.0f / 256.0f)

// --- f16 helpers: RN hi + RN residual lo ---
__device__ __forceinline__ void f16_split(float f, _Float16& hi, _Float16& lo) {
    hi = (_Float16)f;                    // v_cvt_f16_f32 (RN)
    lo = (_Float16)(f - (float)hi);
}

#define MFMA16(a, b, c) __builtin_amdgcn_mfma_f32_16x16x32_f16((a), (b), (c), 0, 0, 0)

// ---------------------------------------------------------------------------
// wprep: (a) W=[Wq|Wk|Wv] (512x192) -> B-frag order, f16 RN (hi only —
//        2-pass scheme; B-side RN error 2^-12 vs bf16-trunc 2^-9).
//        (b) zero K pad rows + Vs.  (c) Vf init: zeros + f16 ones plane nt=4.
// W frag layout: [kt(16)][nt(12)][lane(64)][j(8)]
// Vf layout:     [b(2)][jt(5)][nt(5)][lane(64)][jj(8)]
// (Byte-exact R9 — proven 97.8 µs / absmax 7.8e-3.)
// ---------------------------------------------------------------------------
__global__ __launch_bounds__(256) void wprep_kernel(
    const float* __restrict__ Wq, const float* __restrict__ Wk,
    const float* __restrict__ Wv,
    _Float16* __restrict__ Wf, _Float16* __restrict__ Khi,
    _Float16* __restrict__ Vf, float* __restrict__ Vs)
{
    const int gtid = blockIdx.x * 256 + threadIdx.x;   // [0, 12288)
    const int L = gtid & 63;
    {
        const int nt = (gtid >> 6) % 12;
        const int kt = gtid / 768;
        const int n = nt * 16 + (L & 15);
        const int kbase = kt * 32 + (L >> 4) * 8;
        const float* src; int col;
        if (n < 64)       { src = Wq; col = n; }
        else if (n < 128) { src = Wk; col = n - 64; }
        else              { src = Wv; col = n - 128; }
        half8 sh;
#pragma unroll
        for (int j = 0; j < 8; ++j)
            sh[j] = (_Float16)src[(size_t)(kbase + j) * HD + col];
        *(half8*)(Wf + (size_t)gtid * 8) = sh;
    }
    if (gtid < 6144) {   // zero 768 K-pad rows x 128 B
        const int p = gtid >> 3, o = gtid & 7;
        const int b = p / 192, q = p - b * 192;
        const size_t row = (size_t)b * KROWS + (q < 64 ? q : 4096 + q);
        const half8 z = {0, 0, 0, 0, 0, 0, 0, 0};
        *(half8*)(Khi + row * HD + o * 8) = z;
    }
    if (gtid < 3200) {   // Vf init: zeros; nt==4 plane gets ones-pattern
        const int rem = gtid % 1600;
        const int jt = rem / 320;
        const int nt = (rem / 64) % 5;
        half8 sh = {0, 0, 0, 0, 0, 0, 0, 0};
        if (nt == 4 && (L & 15) == 0) {
#pragma unroll
            for (int jj = 0; jj < 8; ++jj) {
                const int j = jt * 32 + (L >> 4) * 8 + jj;
                if (j < 129) sh[jj] = (_Float16)1.0f;
            }
        }
        *(half8*)(Vf + (size_t)gtid * 8) = sh;
    }
    if (gtid < 128) Vs[gtid] = 0.f;
}

// ---------------------------------------------------------------------------
// proj: QKV = x @ W + b, 2-pass f16 MFMA ((xhi + xlo) * Whi-RN).
// grid 512 x 512 (8 waves) = 4096 waves = 16/CU.
// Block = 16 rows. Wave = nt-triple (w&3) x k-half (w>>2, 8 kt each);
// k-split partials combined via LDS. TLP is the latency hider.
// Epilogue (waves 0-3): Q f16 hi+lo, K f16 hi, V -> LDS -> Vsum + V-frags.
// (Byte-exact R9.)
// ---------------------------------------------------------------------------
__global__ __launch_bounds__(512) void proj_kernel(
    const float* __restrict__ x, const _Float16* __restrict__ Wf,
    const float* __restrict__ bq, const float* __restrict__ bk,
    const float* __restrict__ bv,
    _Float16* __restrict__ Qhi, _Float16* __restrict__ Qlo,
    _Float16* __restrict__ Khi, _Float16* __restrict__ Vf,
    float* __restrict__ Vs)
{
    __shared__ float parts[4][3][64][4];   // k-half-1 partials (12 KB)
    __shared__ float V_lds[16][68];
    const int tid = threadIdx.x;
    const int L = tid & 63;
    const int w = tid >> 6;              // wave 0..7
    const int m = L & 15, kg = L >> 4;
    const int blk = blockIdx.x;          // 0..511
    const int r0 = blk * 16;
    const int b = blk >> 8;
    const int t3 = w & 3;                // nt-triple: nts 3*t3..3*t3+2
    const int h = w >> 2;                // k-half: kts 8h..8h+7

    const float* xp = x + (size_t)(r0 + m) * NE + h * 256 + kg * 8;
    const _Float16* wfb = Wf + ((size_t)(h * 8) * 12 + t3 * 3) * 512 + L * 8;

    f32x4 acc[3];
#pragma unroll
    for (int t = 0; t < 3; ++t) acc[t] = (f32x4){0.f, 0.f, 0.f, 0.f};

#pragma unroll
    for (int kt = 0; kt < 8; ++kt) {
        const float4 x0 = *(const float4*)(xp + kt * 32);
        const float4 x1 = *(const float4*)(xp + kt * 32 + 4);
        const float xv[8] = {x0.x, x0.y, x0.z, x0.w, x1.x, x1.y, x1.z, x1.w};
        half8 ahi, alo;
#pragma unroll
        for (int j = 0; j < 8; ++j) {
            _Float16 hh, ll; f16_split(xv[j], hh, ll);
            ahi[j] = hh; alo[j] = ll;
        }
#pragma unroll
        for (int t = 0; t < 3; ++t) {
            const half8 wv = *(const half8*)(wfb + (size_t)kt * 6144 + t * 512);
            acc[t] = MFMA16(ahi, wv, acc[t]);
            acc[t] = MFMA16(alo, wv, acc[t]);
        }
    }

    if (h == 1) {
#pragma unroll
        for (int t = 0; t < 3; ++t)
            *(f32x4*)(&parts[t3][t][L][0]) = acc[t];
    }
    __syncthreads();

    if (h == 0) {
#pragma unroll
        for (int t = 0; t < 3; ++t) {
            const f32x4 p = *(const f32x4*)(&parts[t3][t][L][0]);
            acc[t] += p;
            const int nt = t3 * 3 + t;
            const int cgc = nt * 16 + m;     // global col 0..191
            const float bias = (cgc < 64) ? bq[cgc]
                             : (cgc < 128) ? bk[cgc - 64] : bv[cgc - 128];
#pragma unroll
            for (int r = 0; r < 4; ++r) {
                const int gr = r0 + kg * 4 + r;
                const float val = acc[t][r] + bias;
                if (cgc < 64) {
                    _Float16 hh, ll; f16_split(val, hh, ll);
                    Qhi[(size_t)gr * HD + cgc] = hh;
                    Qlo[(size_t)gr * HD + cgc] = ll;
                } else if (cgc < 128) {
                    const int d = cgc - 64, n = gr & 4095;
                    Khi[((size_t)b * KROWS + KOFF + n) * HD + d] = (_Float16)val;
                } else {
                    V_lds[kg * 4 + r][cgc - 128] = val;
                }
            }
        }
    }
    __syncthreads();

    // Vsum: one atomic per dim
    if (tid < 64) {
        float s = 0.f;
#pragma unroll
        for (int r = 0; r < 16; ++r) s += V_lds[r][tid];
        atomicAdd(&Vs[b * HD + tid], s);
    }

    // V-frag emission for rows < 129 (16-row blocks: local 0..7 -> two
    // kg-chunks of jt=local>>1; local 8 -> j==128 only).
    {
        const int local = blk & 255;
        if (local < 8 && w < 4) {
            const int jt = local >> 1;
            if ((kg >> 1) == (local & 1)) {   // this block owns this kg pair
                const int nt = w;             // V ntile 0..3
                half8 sh;
#pragma unroll
                for (int jj = 0; jj < 8; ++jj) {
                    const int lrow = (kg - (local & 1) * 2) * 8 + jj;  // 0..15
                    sh[jj] = (_Float16)V_lds[lrow][nt * 16 + m];
                }
                const size_t fo = ((size_t)((b * 25 + jt * 5 + nt) * 64 + L)) * 8;
                *(half8*)(Vf + fo) = sh;
            }
        } else if (local == 8 && w < 4 && kg == 0) {
            const int nt = w;
            half8 sh = {0, 0, 0, 0, 0, 0, 0, 0};
            sh[0] = (_Float16)V_lds[0][nt * 16 + m];   // j == 128
            const size_t fo = ((size_t)((b * 25 + 4 * 5 + nt) * 64 + L)) * 8;
            *(half8*)(Vf + fo) = sh;
        }
    }
}

// ---------------------------------------------------------------------------
// attn: grid 512 (b = blk>>8, 16 queries/block), block 256 (4 waves).
// f16 2-pass, all global loads upfront. Phase 1: S = (qhi+qlo).Khi^T,
// w' = (exp(s)-1)/256 -> LDS f16 hi/lo. Phase 2: [out|den] = wt @ [V|1|0];
// wave wv owns ntile wv; wave 0 also the ones-column tile.
// (Byte-exact R9. R12/R13's lo-dropping variants failed at absmax 1.17
// with a bug inspection could not locate — do not re-drop without a
// single-variable bisect from this base.)
// ---------------------------------------------------------------------------
__global__ __launch_bounds__(256) void attn_kernel(
    const _Float16* __restrict__ Qhi, const _Float16* __restrict__ Qlo,
    const _Float16* __restrict__ Khi, const _Float16* __restrict__ Vf,
    const float* __restrict__ Vs, float* __restrict__ out)
{
    __shared__ __align__(16) _Float16 wt_hi[16 * 168];
    __shared__ __align__(16) _Float16 wt_lo[16 * 168];
    __shared__ float den_lds[16];

    const int tid = threadIdx.x;
    const int L = tid & 63;
    const int w = tid >> 6;
    const int m = L & 15, kg = L >> 4;
    const int b = blockIdx.x >> 8;
    const int n0 = (blockIdx.x & 255) * 16;

    // ---- upfront load issuance (all independent) ----
    const _Float16* qp  = Qhi + ((size_t)(b * NN + n0 + m)) * HD + kg * 8;
    const _Float16* qp2 = Qlo + ((size_t)(b * NN + n0 + m)) * HD + kg * 8;
    const half8 qhi0 = *(const half8*)(qp);
    const half8 qhi1 = *(const half8*)(qp + 32);
    const half8 qlo0 = *(const half8*)(qp2);
    const half8 qlo1 = *(const half8*)(qp2 + 32);

    int kts[3]; int nkt;
    if (w == 3) { kts[0] = 3; kts[1] = 7; kts[2] = 8; nkt = 3; }
    else        { kts[0] = w; kts[1] = w + 4; kts[2] = 0; nkt = 2; }

    const _Float16* KB = Khi + (size_t)b * KROWS * HD;
    half8 kh0[3], kh1[3];
#pragma unroll
    for (int i = 0; i < 3; ++i) {
        if (i < nkt) {                   // wave-uniform branch
            const _Float16* kp = KB + (size_t)(n0 + kts[i] * 16 + m) * HD + kg * 8;
            kh0[i] = *(const half8*)(kp);
            kh1[i] = *(const half8*)(kp + 32);
        }
    }

    half8 vhi[5], vh4[5];
#pragma unroll
    for (int jt = 0; jt < 5; ++jt) {
        const size_t fo = ((size_t)((b * 25 + jt * 5 + w) * 64 + L)) * 8;
        vhi[jt] = *(const half8*)(Vf + fo);
    }
    if (w == 0) {                        // wave-uniform
#pragma unroll
        for (int jt = 0; jt < 5; ++jt) {
            const size_t fo4 = ((size_t)((b * 25 + jt * 5 + 4) * 64 + L)) * 8;
            vh4[jt] = *(const half8*)(Vf + fo4);
        }
    }

    // zero the (q,j) weight buffer (j in [129,168) must read as 0)
    for (int i = tid; i < (16 * 168) / 2; i += 256) {
        ((int*)wt_hi)[i] = 0;
        ((int*)wt_lo)[i] = 0;
    }
    __syncthreads();

    // ---- phase 1 ----
#pragma unroll
    for (int i = 0; i < 3; ++i) {
        if (i < nkt) {
            f32x4 acc = (f32x4){0.f, 0.f, 0.f, 0.f};
            acc = MFMA16(qhi0, kh0[i], acc);
            acc = MFMA16(qhi1, kh1[i], acc);
            acc = MFMA16(qlo0, kh0[i], acc);
            acc = MFMA16(qlo1, kh1[i], acc);
            const int l = kts[i] * 16 + m;
#pragma unroll
            for (int r = 0; r < 4; ++r) {
                const int q = kg * 4 + r;
                const int j = l - q;
                if (j >= 0 && j < 129) {
                    const float wval = (__expf(acc[r]) - 1.0f) * WSCALE;
                    _Float16 hh, ll; f16_split(wval, hh, ll);
                    wt_hi[q * 168 + j] = hh;
                    wt_lo[q * 168 + j] = ll;
                }
            }
        }
    }
    __syncthreads();

    // ---- phase 2 ----
    f32x4 oacc = (f32x4){0.f, 0.f, 0.f, 0.f};
    f32x4 dacc = (f32x4){0.f, 0.f, 0.f, 0.f};
#pragma unroll
    for (int jt = 0; jt < 5; ++jt) {
        const half8 whi = *(const half8*)(wt_hi + m * 168 + jt * 32 + kg * 8);
        const half8 wlo = *(const half8*)(wt_lo + m * 168 + jt * 32 + kg * 8);
        oacc = MFMA16(whi, vhi[jt], oacc);
        oacc = MFMA16(wlo, vhi[jt], oacc);
        if (w == 0) {
            dacc = MFMA16(whi, vh4[jt], dacc);
            dacc = MFMA16(wlo, vh4[jt], dacc);
        }
    }
    if (w == 0 && m == 0) {
#pragma unroll
        for (int r = 0; r < 4; ++r) den_lds[kg * 4 + r] = dacc[r];
    }
    __syncthreads();

    // ---- epilogue (unscale: num = 256*oacc, den = 4096 + 256*dacc) ----
    {
        const float vs = Vs[b * HD + w * 16 + m];
#pragma unroll
        for (int r = 0; r < 4; ++r) {
            const int q = kg * 4 + r;
            const float val = (vs + 256.0f * oacc[r])
                            / (4096.f + 256.0f * den_lds[q]);
            out[((size_t)(b * NN + n0 + q)) * HD + w * 16 + m] = val;
        }
    }
}

// ---------------------------------------------------------------------------
extern "C" void kernel_launch(void* const* d_in, const int* in_sizes, int n_in,
                              void* d_out, int out_size, void* d_ws, size_t ws_size,
                              hipStream_t stream)
{
    const float* x  = (const float*)d_in[0];
    const float* Wq = (const float*)d_in[1];
    const float* bq = (const float*)d_in[2];
    const float* Wk = (const float*)d_in[3];
    const float* bk = (const float*)d_in[4];
    const float* Wv = (const float*)d_in[5];
    const float* bv = (const float*)d_in[6];
    float* out = (float*)d_out;

    char* ws = (char*)d_ws;
    float*     Vs  = (float*)(ws + 0);              //      512 B
    _Float16*  Khi = (_Float16*)(ws + 512);         // 1097728 B
    _Float16*  Qhi = (_Float16*)(ws + 1098240);     // 1048576 B
    _Float16*  Qlo = (_Float16*)(ws + 2146816);     // 1048576 B
    _Float16*  Wf  = (_Float16*)(ws + 3195392);     //  196608 B
    _Float16*  Vf  = (_Float16*)(ws + 3392000);     //   51200 B

    wprep_kernel<<<48, 256, 0, stream>>>(Wq, Wk, Wv, Wf, Khi, Vf, Vs);
    proj_kernel<<<512, 512, 0, stream>>>(x, Wf, bq, bk, bv,
                                         Qhi, Qlo, Khi, Vf, Vs);
    attn_kernel<<<512, 256, 0, stream>>>(Qhi, Qlo, Khi, Vf, Vs, out);
}